// Round 5
// baseline (2002.632 us; speedup 1.0000x reference)
//
#include <hip/hip_runtime.h>
#include <hip/hip_bf16.h>

#define S_LEN 1024
#define BATCH 2048
#define HID   64
#define MB    2               // batch rows per block
#define NBLK  (BATCH / MB)    // 1024 blocks -> 4 per CU (4 indep barrier groups)
#define NTHR  (MB * HID)      // 128 threads = 2 waves

typedef _Float16 half8 __attribute__((ext_vector_type(8)));
typedef float    f32x4 __attribute__((ext_vector_type(4)));

#define L2E 1.4426950408889634f
#define HSTRIDE 72            // h row stride in halves (144 B)

__global__ __launch_bounds__(NTHR) void lstm_kernel(
    const float* __restrict__ x,      // (S, BATCH)
    const float* __restrict__ W_ih,   // (256,1)
    const float* __restrict__ W_hh,   // (256,64)
    const float* __restrict__ b_ih,   // (256,)
    const float* __restrict__ b_hh,   // (256,)
    const float* __restrict__ fc1_w,  // (128,64)
    const float* __restrict__ fc1_b,  // (128,)
    const float* __restrict__ fc2_w,  // (5,128)
    const float* __restrict__ fc2_b,  // (5,)
    float* __restrict__ out)          // (BATCH,5)
{
    // h double-buffered: 2 real rows (batches), fp16
    __shared__ __align__(16) _Float16 h_buf[2][MB * HSTRIDE];        // 576 B
    __shared__ __align__(16) float    head_lds[MB * HID + MB * 128]; // c + fc1 out

    const int tid  = threadIdx.x;
    const int lane = tid & 63;
    const int wave = tid >> 6;        // 0..1
    const int l15  = lane & 15;
    const int quad = lane >> 4;       // 0..3
    const int b0   = blockIdx.x * MB;

    // ---- zero both h buffers (h0 = 0) ----
    {
        unsigned* hz = (unsigned*)&h_buf[0][0];
        for (int i = tid; i < 2 * MB * HSTRIDE / 2; i += NTHR) hz[i] = 0u;
    }

    // ---- stationary W_hh B-fragments ----
    // wave w owns gate-columns [32w, 32w+32) of each gate block: tiles (g, h2),
    // cols = g*64 + 32w + 16*h2 + l15.  B-frag (16x16x32 f16): lane holds
    // B[k=quad*8+j][n=l15] = W_hh[col][k]; k-tile kt adds 32.
    // Pre-scaled by -log2e (sigmoid) / -2log2e (tanh on g gate).
    half8 wfrag[4][2][2];
    #pragma unroll
    for (int g = 0; g < 4; ++g) {
        const float s = (g == 2) ? (-2.0f * L2E) : (-L2E);
        #pragma unroll
        for (int h2 = 0; h2 < 2; ++h2) {
            const float* wr = W_hh + (g * 64 + 32 * wave + 16 * h2 + l15) * HID + quad * 8;
            #pragma unroll
            for (int kt = 0; kt < 2; ++kt) {
                half8 f;
                #pragma unroll
                for (int j = 0; j < 8; ++j) f[j] = (_Float16)(wr[kt * 32 + j] * s);
                wfrag[g][h2][kt] = f;
            }
        }
    }

    // ---- elementwise ownership: thread handles b = quad>>1, u = 32w + 16(quad&1) + l15 ----
    const int bb = quad >> 1;
    const int u  = 32 * wave + 16 * (quad & 1) + l15;
    float wih_s[4], bias_s[4];
    #pragma unroll
    for (int g = 0; g < 4; ++g) {
        const int n = g * 64 + u;
        const float s = (g == 2) ? (-2.0f * L2E) : (-L2E);
        wih_s[g]  = W_ih[n] * s;
        bias_s[g] = (b_ih[n] + b_hh[n]) * s;
    }

    const float* xcol = x + b0 + bb;
    float c = 0.0f;

    // ---- 4-deep x prefetch pipeline ----
    float xq[4];
    #pragma unroll
    for (int j = 0; j < 4; ++j) xq[j] = xcol[(size_t)j * BATCH];

    // ---- anti-phase stagger: decorrelate co-resident blocks' barrier phases ----
    {
        const unsigned d = (blockIdx.x ^ (blockIdx.x >> 2) ^ (blockIdx.x >> 4)
                            ^ (blockIdx.x >> 8)) & 3u;
        if (d & 1u) __builtin_amdgcn_s_sleep(2);   // ~128 cyc
        if (d & 2u) __builtin_amdgcn_s_sleep(4);   // ~256 cyc
    }

    __syncthreads();

    auto body = [&](int base, int j, const _Float16* hr, _Float16* hw) {
        const float xv = xq[j];
        int sp = base + j + 4;
        if (sp > S_LEN - 1) sp = S_LEN - 1;        // clamp (tail values unused)
        xq[j] = xcol[(size_t)sp * BATCH];

        // ---- MFMA with replicated A: A[m][k] = h[m>>3][k] ----
        // C[row=quad*4+r][col=l15]: batch = row>>3 = quad>>1, identical over r.
        const _Float16* arow = hr + (l15 >> 3) * HSTRIDE + quad * 8;
        half8 a0 = *(const half8*)(arow);          // k 0..31
        half8 a1 = *(const half8*)(arow + 32);     // k 32..63

        f32x4 acc[4][2];
        #pragma unroll
        for (int g = 0; g < 4; ++g) {
            #pragma unroll
            for (int h2 = 0; h2 < 2; ++h2) {
                f32x4 a = {0.f, 0.f, 0.f, 0.f};
                a = __builtin_amdgcn_mfma_f32_16x16x32_f16(a0, wfrag[g][h2][0], a, 0, 0, 0);
                a = __builtin_amdgcn_mfma_f32_16x16x32_f16(a1, wfrag[g][h2][1], a, 0, 0, 0);
                acc[g][h2] = a;
            }
        }

        // ---- elementwise: this thread's gate g value = acc[g][quad&1][0] ----
        const int hh = quad & 1;
        const float gi = acc[0][hh][0] + __builtin_fmaf(xv, wih_s[0], bias_s[0]);
        const float gf = acc[1][hh][0] + __builtin_fmaf(xv, wih_s[1], bias_s[1]);
        const float gg = acc[2][hh][0] + __builtin_fmaf(xv, wih_s[2], bias_s[2]);
        const float go = acc[3][hh][0] + __builtin_fmaf(xv, wih_s[3], bias_s[3]);

        const float i_ = __builtin_amdgcn_rcpf(1.0f + __builtin_amdgcn_exp2f(gi));
        const float f_ = __builtin_amdgcn_rcpf(1.0f + __builtin_amdgcn_exp2f(gf));
        const float g_ = 2.0f * __builtin_amdgcn_rcpf(1.0f + __builtin_amdgcn_exp2f(gg)) - 1.0f;
        const float o_ = __builtin_amdgcn_rcpf(1.0f + __builtin_amdgcn_exp2f(go));

        c = f_ * c + i_ * g_;
        const float th = 2.0f * __builtin_amdgcn_rcpf(
                             1.0f + __builtin_amdgcn_exp2f((-2.0f * L2E) * c)) - 1.0f;
        const float h = o_ * th;

        hw[bb * HSTRIDE + u] = (_Float16)h;
        __syncthreads();   // 2-wave barrier, the only one per step
    };

    _Float16* h0 = &h_buf[0][0];
    _Float16* h1 = &h_buf[1][0];

    for (int base = 0; base < S_LEN; base += 4) {
        body(base, 0, h0, h1);
        body(base, 1, h1, h0);
        body(base, 2, h0, h1);
        body(base, 3, h1, h0);
    }

    // ---------- fused FC head on final cell state (no activation) ----------
    float* c_lds  = head_lds;            // MB*64 floats: [b][u]
    float* h1_lds = head_lds + MB * HID; // MB*128 floats: [b][j]
    c_lds[bb * HID + u] = c;
    __syncthreads();

    for (int idx = tid; idx < MB * 128; idx += NTHR) {
        const int b = idx >> 7, j = idx & 127;
        const float* wrow = fc1_w + j * HID;
        const float* crow = c_lds + b * HID;
        float acc = fc1_b[j];
        #pragma unroll
        for (int k = 0; k < HID; k += 4)
            acc += crow[k] * wrow[k] + crow[k+1] * wrow[k+1]
                 + crow[k+2] * wrow[k+2] + crow[k+3] * wrow[k+3];
        h1_lds[idx] = acc;
    }
    __syncthreads();

    if (tid < MB * 5) {
        const int b = tid / 5, q = tid % 5;
        const float* wrow = fc2_w + q * 128;
        const float* hrow = h1_lds + b * 128;
        float acc = fc2_b[q];
        #pragma unroll 4
        for (int j = 0; j < 128; ++j) acc += hrow[j] * wrow[j];
        out[(b0 + b) * 5 + q] = acc;
    }
}

extern "C" void kernel_launch(void* const* d_in, const int* in_sizes, int n_in,
                              void* d_out, int out_size, void* d_ws, size_t ws_size,
                              hipStream_t stream) {
    const float* x     = (const float*)d_in[0];
    const float* W_ih  = (const float*)d_in[1];
    const float* W_hh  = (const float*)d_in[2];
    const float* b_ih  = (const float*)d_in[3];
    const float* b_hh  = (const float*)d_in[4];
    const float* fc1_w = (const float*)d_in[5];
    const float* fc1_b = (const float*)d_in[6];
    const float* fc2_w = (const float*)d_in[7];
    const float* fc2_b = (const float*)d_in[8];
    float* out = (float*)d_out;

    lstm_kernel<<<NBLK, NTHR, 0, stream>>>(x, W_ih, W_hh, b_ih, b_hh,
                                           fc1_w, fc1_b, fc2_w, fc2_b, out);
}

// Round 6
// 450.213 us; speedup vs baseline: 4.4482x; 4.4482x over previous
//
#include <hip/hip_runtime.h>
#include <hip/hip_bf16.h>

#define S_LEN 1024
#define BATCH 2048
#define HID   64
#define MB    4               // batch rows per block
#define NBLK  (BATCH / MB)    // 512 blocks -> 2 per CU
#define NTHR  (MB * HID)      // 256 threads = 4 waves

typedef _Float16 half8 __attribute__((ext_vector_type(8)));
typedef float    f32x4 __attribute__((ext_vector_type(4)));

#define L2E 1.4426950408889634f
#define HSTRIDE 72            // h row stride in halves (144 B)

// launch_bounds(256, 2): 2 waves/EU = 8 waves/CU = 2 blocks/CU (matches grid).
// The min-waves arg is LOAD-BEARING: without it the allocator caps VGPRs and
// rematerializes the stationary W_hh fragments inside the loop (round-5: 6x).
__global__ __launch_bounds__(NTHR, 2) void lstm_kernel(
    const float* __restrict__ x,      // (S, BATCH)
    const float* __restrict__ W_ih,   // (256,1)
    const float* __restrict__ W_hh,   // (256,64)
    const float* __restrict__ b_ih,   // (256,)
    const float* __restrict__ b_hh,   // (256,)
    const float* __restrict__ fc1_w,  // (128,64)
    const float* __restrict__ fc1_b,  // (128,)
    const float* __restrict__ fc2_w,  // (5,128)
    const float* __restrict__ fc2_b,  // (5,)
    float* __restrict__ out)          // (BATCH,5)
{
    // h double-buffered: 4 real rows (batches), fp16
    __shared__ __align__(16) _Float16 h_buf[2][MB * HSTRIDE];        // 1152 B
    __shared__ __align__(16) float    head_lds[MB * HID + MB * 128]; // c + fc1 out

    const int tid  = threadIdx.x;
    const int lane = tid & 63;
    const int wave = tid >> 6;        // 0..3
    const int l15  = lane & 15;
    const int quad = lane >> 4;       // 0..3
    const int b0   = blockIdx.x * MB;

    // ---- zero both h buffers (h0 = 0) ----
    {
        unsigned* hz = (unsigned*)&h_buf[0][0];
        for (int i = tid; i < 2 * MB * HSTRIDE / 2; i += NTHR) hz[i] = 0u;
    }

    // ---- stationary W_hh B-fragments, per-wave unit slice (32 VGPRs) ----
    // wave w, gate g: frag col n=l15 <-> W_hh row g*64 + 16w + l15.
    // B-frag (16x16x32 f16): lane holds B[k=quad*8+j][n=l15]; k-tile kt adds 32.
    // Pre-scaled by -log2e (sigmoid) / -2log2e (tanh on g gate).
    half8 wfrag[4][2];
    #pragma unroll
    for (int g = 0; g < 4; ++g) {
        const float s = (g == 2) ? (-2.0f * L2E) : (-L2E);
        const float* wr = W_hh + (g * 64 + 16 * wave + l15) * HID + quad * 8;
        #pragma unroll
        for (int kt = 0; kt < 2; ++kt) {
            half8 f;
            #pragma unroll
            for (int j = 0; j < 8; ++j) f[j] = (_Float16)(wr[kt * 32 + j] * s);
            wfrag[g][kt] = f;
        }
    }

    // ---- elementwise ownership: thread (quad,l15) handles b=quad, u=16*wave+l15 ----
    const int u = 16 * wave + l15;
    float wih_s[4], bias_s[4];
    #pragma unroll
    for (int g = 0; g < 4; ++g) {
        const int n = g * 64 + u;
        const float s = (g == 2) ? (-2.0f * L2E) : (-L2E);
        wih_s[g]  = W_ih[n] * s;
        bias_s[g] = (b_ih[n] + b_hh[n]) * s;
    }

    const float* xcol = x + b0 + quad;   // this thread's batch row
    float c = 0.0f;

    // ---- 4-deep x prefetch pipeline ----
    float xq[4];
    #pragma unroll
    for (int j = 0; j < 4; ++j) xq[j] = xcol[(size_t)j * BATCH];

    // ---- anti-phase stagger: decorrelate the 2 co-resident blocks' barriers ----
    {
        const unsigned d = (blockIdx.x ^ (blockIdx.x >> 1) ^ (blockIdx.x >> 3)
                            ^ (blockIdx.x >> 7)) & 1u;
        if (d) __builtin_amdgcn_s_sleep(3);   // ~192 cyc one-time offset
    }

    __syncthreads();

    auto body = [&](int base, int j, const _Float16* hr, _Float16* hw) {
        const float xv = xq[j];
        int sp = base + j + 4;
        if (sp > S_LEN - 1) sp = S_LEN - 1;    // clamp (tail values unused)
        xq[j] = xcol[(size_t)sp * BATCH];

        // ---- MFMA with replicated A: A[m][k] = h[m>>2][k] ----
        // C[row=quad*4+r][col=l15] = gates[batch=quad][unit], identical over r.
        const _Float16* arow = hr + (l15 >> 2) * HSTRIDE + quad * 8;
        half8 a0 = *(const half8*)(arow);        // k 0..31
        half8 a1 = *(const half8*)(arow + 32);   // k 32..63

        // K-split: two INDEPENDENT accumulators per gate -> 8 independent MFMAs
        // (round-4 counters showed 19 cyc/MFMA latency exposure on 2-chains).
        // accA's C-init carries the x*W_ih + bias term (splat; off the tail chain).
        f32x4 accA[4], accB[4];
        #pragma unroll
        for (int g = 0; g < 4; ++g) {
            const float gb = __builtin_fmaf(xv, wih_s[g], bias_s[g]);
            f32x4 ca = {gb, gb, gb, gb};
            f32x4 cb = {0.f, 0.f, 0.f, 0.f};
            accA[g] = __builtin_amdgcn_mfma_f32_16x16x32_f16(a0, wfrag[g][0], ca, 0, 0, 0);
            accB[g] = __builtin_amdgcn_mfma_f32_16x16x32_f16(a1, wfrag[g][1], cb, 0, 0, 0);
        }

        // ---- elementwise: gate g value = accA[g][0] + accB[g][0] ----
        const float gi = accA[0][0] + accB[0][0];
        const float gf = accA[1][0] + accB[1][0];
        const float gg = accA[2][0] + accB[2][0];
        const float go = accA[3][0] + accB[3][0];

        const float i_ = __builtin_amdgcn_rcpf(1.0f + __builtin_amdgcn_exp2f(gi));
        const float f_ = __builtin_amdgcn_rcpf(1.0f + __builtin_amdgcn_exp2f(gf));
        const float g_ = 2.0f * __builtin_amdgcn_rcpf(1.0f + __builtin_amdgcn_exp2f(gg)) - 1.0f;
        const float o_ = __builtin_amdgcn_rcpf(1.0f + __builtin_amdgcn_exp2f(go));

        c = f_ * c + i_ * g_;
        const float th = 2.0f * __builtin_amdgcn_rcpf(
                             1.0f + __builtin_amdgcn_exp2f((-2.0f * L2E) * c)) - 1.0f;
        const float h = o_ * th;

        hw[quad * HSTRIDE + u] = (_Float16)h;
        __syncthreads();   // the ONLY barrier per step
    };

    _Float16* h0 = &h_buf[0][0];
    _Float16* h1 = &h_buf[1][0];

    for (int base = 0; base < S_LEN; base += 4) {
        body(base, 0, h0, h1);
        body(base, 1, h1, h0);
        body(base, 2, h0, h1);
        body(base, 3, h1, h0);
    }

    // ---------- fused FC head on final cell state (no activation) ----------
    float* c_lds  = head_lds;            // MB*64 floats: [b][u]
    float* h1_lds = head_lds + MB * HID; // MB*128 floats: [b][j]
    c_lds[quad * HID + u] = c;
    __syncthreads();

    for (int idx = tid; idx < MB * 128; idx += NTHR) {
        const int b = idx >> 7, j = idx & 127;
        const float* wrow = fc1_w + j * HID;
        const float* crow = c_lds + b * HID;
        float acc = fc1_b[j];
        #pragma unroll
        for (int k = 0; k < HID; k += 4)
            acc += crow[k] * wrow[k] + crow[k+1] * wrow[k+1]
                 + crow[k+2] * wrow[k+2] + crow[k+3] * wrow[k+3];
        h1_lds[idx] = acc;
    }
    __syncthreads();

    if (tid < MB * 5) {
        const int b = tid / 5, q = tid % 5;
        const float* wrow = fc2_w + q * 128;
        const float* hrow = h1_lds + b * 128;
        float acc = fc2_b[q];
        #pragma unroll 4
        for (int j = 0; j < 128; ++j) acc += hrow[j] * wrow[j];
        out[(b0 + b) * 5 + q] = acc;
    }
}

extern "C" void kernel_launch(void* const* d_in, const int* in_sizes, int n_in,
                              void* d_out, int out_size, void* d_ws, size_t ws_size,
                              hipStream_t stream) {
    const float* x     = (const float*)d_in[0];
    const float* W_ih  = (const float*)d_in[1];
    const float* W_hh  = (const float*)d_in[2];
    const float* b_ih  = (const float*)d_in[3];
    const float* b_hh  = (const float*)d_in[4];
    const float* fc1_w = (const float*)d_in[5];
    const float* fc1_b = (const float*)d_in[6];
    const float* fc2_w = (const float*)d_in[7];
    const float* fc2_b = (const float*)d_in[8];
    float* out = (float*)d_out;

    lstm_kernel<<<NBLK, NTHR, 0, stream>>>(x, W_ih, W_hh, b_ih, b_hh,
                                           fc1_w, fc1_b, fc2_w, fc2_b, out);
}